// Round 10
// baseline (100.267 us; speedup 1.0000x reference)
//
#include <hip/hip_runtime.h>

#define NUM_K 1024
#define DIM 256
#define HWDIM 1024
#define BETA 0.25f
#define NTOT 8388608  // 32*256*32*32
#define DIST_C 0.25f  // keeps dist = ||e||^2 + C - 2 x.e positive
#define ESCALE 512.0f // codebook stored as e*512 in fp8 e4m3
#define NEG2_OVER_ESCALE (-0.00390625f)  // -2/512

typedef __attribute__((ext_vector_type(4))) float fx4;
typedef unsigned int u32;

// d_ws (floats): [0] loss acc | [64..1088) enorm+C (exact fp32) |
//   [1088..66624) fp8 frag-ordered codebook (256 KB): [gc=code/16][s=0..7][lane=0..63][8B]
//   code = gc*16+(lane&15), dim = s*32+(lane>>4)*8+e  -> staging & ds_read both linear.

// fused prep: blocks [0,128) build fp8 frag codebook; blocks [128,384) exact enorm
__global__ void prep_kernel(const float* __restrict__ wgt, float* __restrict__ ws) {
    if (blockIdx.x < 128) {
        int g = blockIdx.x * 256 + threadIdx.x;       // 0..32767, 8 bytes each
        int lane = g & 63, s = (g >> 6) & 7, gc = g >> 9;
        int code = gc * 16 + (lane & 15);
        int d0 = s * 32 + (lane >> 4) * 8;
        const float* p = wgt + (size_t)code * DIM + d0;
        float4 a = *reinterpret_cast<const float4*>(p);
        float4 b = *reinterpret_cast<const float4*>(p + 4);
        u32 w0 = 0, w1 = 0;
        w0 = __builtin_amdgcn_cvt_pk_fp8_f32(a.x * ESCALE, a.y * ESCALE, w0, false);
        w0 = __builtin_amdgcn_cvt_pk_fp8_f32(a.z * ESCALE, a.w * ESCALE, w0, true);
        w1 = __builtin_amdgcn_cvt_pk_fp8_f32(b.x * ESCALE, b.y * ESCALE, w1, false);
        w1 = __builtin_amdgcn_cvt_pk_fp8_f32(b.z * ESCALE, b.w * ESCALE, w1, true);
        u32* dst = reinterpret_cast<u32*>(ws + 1088) + (size_t)g * 2;
        dst[0] = w0; dst[1] = w1;
    } else {
        int wave = threadIdx.x >> 6, lane = threadIdx.x & 63;
        int k = (blockIdx.x - 128) * 4 + wave;
        if (blockIdx.x == 128 && threadIdx.x == 0) ws[0] = 0.f;
        const float4 v = *reinterpret_cast<const float4*>(wgt + (size_t)k * DIM + lane * 4);
        float s = v.x * v.x + v.y * v.y + v.z * v.z + v.w * v.w;
        #pragma unroll
        for (int off = 32; off > 0; off >>= 1) s += __shfl_down(s, off, 64);
        if (lane == 0) ws[64 + k] = s + DIST_C;
    }
}

__device__ __forceinline__ void gl2lds16(const void* g, void* l) {
    __builtin_amdgcn_global_load_lds(
        (const __attribute__((address_space(1))) u32*)g,
        (__attribute__((address_space(3))) u32*)l, 16, 0, 0);
}

__launch_bounds__(256, 4)
__global__ void vq_kernel(const float* __restrict__ in,
                          const float* __restrict__ wgt,
                          float* __restrict__ ws,
                          float* __restrict__ out) {
    // LDS: [0,32K) per-wave B dbuf (wave w: [w*8K,+4K) and [+4K,+8K));
    //      xs fp8 x-tile (32x256 B = 8K) aliases [0,8K), dead after af-hoist
    //      [32K,36K) enorm ; [36K,+512) cand[4][32] ; [36.5K,+128) idxs
    __shared__ __align__(16) unsigned char smem[37504];
    unsigned char* xs = smem;
    float* eno = reinterpret_cast<float*>(smem + 32768);
    float (*cand)[32] = reinterpret_cast<float (*)[32]>(smem + 36864);
    int* idxs = reinterpret_cast<int*>(smem + 37376);

    const int tid = threadIdx.x;
    const int lane = tid & 63;
    const int wv = tid >> 6;        // 4 waves: wave w owns codes [w*256, +256)
    const int tx = lane & 15;
    const int tz = lane >> 4;
    const int bid = blockIdx.x;
    const int bb = bid >> 5;            // batch 0..31
    const int hw0 = (bid & 31) << 5;    // 32 hw positions per block
    const float* inb = in + (size_t)bb * (DIM * HWDIM) + hw0;

    // ---- stage enorm -> LDS ----
    reinterpret_cast<float4*>(eno)[tid] = reinterpret_cast<const float4*>(ws + 64)[tid];

    // ---- stage x: fp32 [d][hw] -> fp8 [row][d] LDS (XOR-swizzled); sum x^2 ----
    float xsq = 0.f;
    {
        int hw4 = (tid & 7) << 2;       // 4 rows
        int dp = tid >> 3;              // 0..31 d-quads
        #pragma unroll
        for (int it = 0; it < 2; ++it) {
            int d0 = dp * 4 + it * 128;
            float4 r0 = *reinterpret_cast<const float4*>(inb + (size_t)(d0 + 0) * HWDIM + hw4);
            float4 r1 = *reinterpret_cast<const float4*>(inb + (size_t)(d0 + 1) * HWDIM + hw4);
            float4 r2 = *reinterpret_cast<const float4*>(inb + (size_t)(d0 + 2) * HWDIM + hw4);
            float4 r3 = *reinterpret_cast<const float4*>(inb + (size_t)(d0 + 3) * HWDIM + hw4);
            xsq += r0.x * r0.x + r0.y * r0.y + r0.z * r0.z + r0.w * r0.w
                 + r1.x * r1.x + r1.y * r1.y + r1.z * r1.z + r1.w * r1.w
                 + r2.x * r2.x + r2.y * r2.y + r2.z * r2.z + r2.w * r2.w
                 + r3.x * r3.x + r3.y * r3.y + r3.z * r3.z + r3.w * r3.w;
            float q0[4] = {r0.x, r0.y, r0.z, r0.w};
            float q1[4] = {r1.x, r1.y, r1.z, r1.w};
            float q2[4] = {r2.x, r2.y, r2.z, r2.w};
            float q3[4] = {r3.x, r3.y, r3.z, r3.w};
            #pragma unroll
            for (int j = 0; j < 4; ++j) {
                int row = hw4 + j;
                u32 w = 0;
                w = __builtin_amdgcn_cvt_pk_fp8_f32(q0[j], q1[j], w, false);
                w = __builtin_amdgcn_cvt_pk_fp8_f32(q2[j], q3[j], w, true);
                *reinterpret_cast<u32*>(xs + row * 256 + (d0 ^ ((row & 7) << 3))) = w;
            }
        }
    }
    __syncthreads();

    // ---- hoist A fragments: row = rf*16+tx (32 rows), k = s*32+tz*8+[0..7] ----
    long af[2][8];
    #pragma unroll
    for (int rf = 0; rf < 2; ++rf) {
        #pragma unroll
        for (int s = 0; s < 8; ++s) {
            int row = rf * 16 + tx;
            int d0 = s * 32 + tz * 8;
            af[rf][s] = *reinterpret_cast<const long*>(xs + row * 256 + (d0 ^ ((row & 7) << 3)));
        }
    }
    __syncthreads();                 // all waves done with xs (dbuf aliases it)
    asm volatile("" ::: "memory");   // af stays in regs; LDS below is overwritten

    // ---- main loop: per-wave dbuf (2x4KB), 16 chunks x 16 codes, 2-ahead vmcnt(4) ----
    unsigned char* buf0 = smem + wv * 8192;
    unsigned char* buf1 = buf0 + 4096;
    const unsigned char* gsrc = reinterpret_cast<const unsigned char*>(ws + 1088)
                                + (size_t)wv * 16 * 4096 + lane * 16;
    auto stage = [&](int ch, unsigned char* b) {
        const unsigned char* sp = gsrc + ch * 4096;
        #pragma unroll
        for (int i = 0; i < 4; ++i)
            gl2lds16(sp + i * 1024, b + i * 1024);
    };
    stage(0, buf0);
    stage(1, buf1);

    float minkey[8];
    #pragma unroll
    for (int q = 0; q < 8; ++q) minkey[q] = 1e30f;

    #pragma unroll
    for (int ch = 0; ch < 16; ++ch) {
        if (ch == 15) asm volatile("s_waitcnt vmcnt(0)" ::: "memory");
        else          asm volatile("s_waitcnt vmcnt(4)" ::: "memory");
        const unsigned char* cb = (ch & 1) ? buf1 : buf0;
        long bf[8];
        #pragma unroll
        for (int s = 0; s < 8; ++s)
            bf[s] = *reinterpret_cast<const long*>(cb + s * 512 + lane * 8);
        const int codebase = wv * 256 + ch * 16 + tx;
        float en = eno[codebase];
        __builtin_amdgcn_s_setprio(1);
        #pragma unroll
        for (int rf = 0; rf < 2; ++rf) {
            fx4 acc = {0.f, 0.f, 0.f, 0.f};
            #pragma unroll
            for (int s = 0; s < 8; ++s)
                acc = __builtin_amdgcn_mfma_f32_16x16x32_fp8_fp8(af[rf][s], bf[s], acc, 0, 0, 0);
            #pragma unroll
            for (int r = 0; r < 4; ++r) {
                float d = fmaf(NEG2_OVER_ESCALE, acc[r], en);
                u32 u = (__builtin_bit_cast(u32, d) & 0xFFFFFC00u) | (u32)codebase;
                minkey[rf * 4 + r] = fminf(minkey[rf * 4 + r], __builtin_bit_cast(float, u));
            }
        }
        __builtin_amdgcn_s_setprio(0);
        if (ch < 14) stage(ch + 2, (ch & 1) ? buf1 : buf0);
    }

    // ---- xsq contribution ----
    #pragma unroll
    for (int off = 32; off > 0; off >>= 1) xsq += __shfl_down(xsq, off, 64);
    if (lane == 0) atomicAdd(&ws[0], xsq);

    // ---- reduce over the 16 col-lanes ----
    #pragma unroll
    for (int q = 0; q < 8; ++q) {
        float v = minkey[q];
        #pragma unroll
        for (int off = 1; off < 16; off <<= 1)
            v = fminf(v, __shfl_xor(v, off, 64));
        minkey[q] = v;
    }
    if (tx == 0) {
        #pragma unroll
        for (int rf = 0; rf < 2; ++rf) {
            #pragma unroll
            for (int r = 0; r < 4; ++r)
                cand[wv][rf * 16 + tz * 4 + r] = minkey[rf * 4 + r];
        }
    }
    __syncthreads();
    if (tid < 64) {
        float bv = 1e30f;
        if (tid < 32)
            bv = fminf(fminf(cand[0][tid], cand[1][tid]),
                       fminf(cand[2][tid], cand[3][tid]));
        u32 ub = __builtin_bit_cast(u32, bv);
        if (tid < 32) idxs[tid] = (int)(ub & 0x3FFu);
        float dsel = (tid < 32)
            ? (__builtin_bit_cast(float, ub & 0xFFFFFC00u) - DIST_C) : 0.f;
        #pragma unroll
        for (int off = 32; off > 0; off >>= 1) dsel += __shfl_down(dsel, off, 64);
        if (tid == 0) atomicAdd(&ws[0], dsel);
    }
    __syncthreads();

    // ---- fused scatter: gather exact fp32 code rows (L2) + coalesced write ----
    {
        int hw4 = (tid & 7) << 2;
        int dq = tid >> 3;                   // 0..31, 8 dims each
        int k0 = idxs[hw4 + 0], k1 = idxs[hw4 + 1];
        int k2 = idxs[hw4 + 2], k3 = idxs[hw4 + 3];
        const float* e0 = wgt + (size_t)k0 * DIM;
        const float* e1 = wgt + (size_t)k1 * DIM;
        const float* e2 = wgt + (size_t)k2 * DIM;
        const float* e3 = wgt + (size_t)k3 * DIM;
        float* outb = out + (size_t)bb * (DIM * HWDIM) + hw0;
        #pragma unroll
        for (int m = 0; m < 2; ++m) {
            int d0 = dq * 8 + m * 4;
            float4 r0 = *reinterpret_cast<const float4*>(e0 + d0);
            float4 r1 = *reinterpret_cast<const float4*>(e1 + d0);
            float4 r2 = *reinterpret_cast<const float4*>(e2 + d0);
            float4 r3 = *reinterpret_cast<const float4*>(e3 + d0);
            float er0[4] = {r0.x, r0.y, r0.z, r0.w};
            float er1[4] = {r1.x, r1.y, r1.z, r1.w};
            float er2[4] = {r2.x, r2.y, r2.z, r2.w};
            float er3[4] = {r3.x, r3.y, r3.z, r3.w};
            #pragma unroll
            for (int qd = 0; qd < 4; ++qd) {
                float4 ev = {er0[qd], er1[qd], er2[qd], er3[qd]};
                *reinterpret_cast<float4*>(outb + (size_t)(d0 + qd) * HWDIM + hw4) = ev;
            }
        }
    }
}

__global__ void loss_kernel(const float* __restrict__ ws, float* __restrict__ out_loss) {
    out_loss[0] = (1.f + BETA) * ws[0] / (float)NTOT;
}

extern "C" void kernel_launch(void* const* d_in, const int* in_sizes, int n_in,
                              void* d_out, int out_size, void* d_ws, size_t ws_size,
                              hipStream_t stream) {
    const float* enc = (const float*)d_in[0];
    const float* wgt = (const float*)d_in[1];
    float* out = (float*)d_out;
    float* ws = (float*)d_ws;

    prep_kernel<<<384, 256, 0, stream>>>(wgt, ws);
    vq_kernel<<<1024, 256, 0, stream>>>(enc, wgt, ws, out);
    loss_kernel<<<1, 1, 0, stream>>>(ws, out + NTOT);
}

// Round 11
// 73.641 us; speedup vs baseline: 1.3616x; 1.3616x over previous
//
#include <hip/hip_runtime.h>

#define NUM_K 1024
#define DIM 256
#define HWDIM 1024
#define BETA 0.25f
#define NTOT 8388608  // 32*256*32*32
#define DIST_C 0.25f  // keeps dist = ||e||^2 + C - 2 x.e positive
#define ESCALE 512.0f // codebook stored as e*512 in fp8 e4m3
#define NEG2_OVER_ESCALE (-0.00390625f)  // -2/512

typedef __attribute__((ext_vector_type(4))) float fx4;
typedef unsigned int u32;

// ws floats: [0] loss acc | [64..1088) enorm+C | [1088..66624) fp8 frag cb (256 KB)
//            | [66624..99392) keys u32[32768]
// cb frag layout: [gc=code/16][s=0..7][lane=0..63][8B]; code = gc*16+(lane&15),
// dim = s*32+(lane>>4)*8+e.  Slice sc = 32 KB contiguous at sc*32768.
#define WS_CB 1088
#define WS_KEYS 66624

// prep: [0,128) fp8 frag codebook | [128,384) enorm+C | [384,512) keys init
__global__ void prep_kernel(const float* __restrict__ wgt, float* __restrict__ ws) {
    if (blockIdx.x < 128) {
        int g = blockIdx.x * 256 + threadIdx.x;       // 0..32767, 8 bytes each
        int lane = g & 63, s = (g >> 6) & 7, gc = g >> 9;
        int code = gc * 16 + (lane & 15);
        int d0 = s * 32 + (lane >> 4) * 8;
        const float* p = wgt + (size_t)code * DIM + d0;
        float4 a = *reinterpret_cast<const float4*>(p);
        float4 b = *reinterpret_cast<const float4*>(p + 4);
        u32 w0 = 0, w1 = 0;
        w0 = __builtin_amdgcn_cvt_pk_fp8_f32(a.x * ESCALE, a.y * ESCALE, w0, false);
        w0 = __builtin_amdgcn_cvt_pk_fp8_f32(a.z * ESCALE, a.w * ESCALE, w0, true);
        w1 = __builtin_amdgcn_cvt_pk_fp8_f32(b.x * ESCALE, b.y * ESCALE, w1, false);
        w1 = __builtin_amdgcn_cvt_pk_fp8_f32(b.z * ESCALE, b.w * ESCALE, w1, true);
        u32* dst = reinterpret_cast<u32*>(ws + WS_CB) + (size_t)g * 2;
        dst[0] = w0; dst[1] = w1;
    } else if (blockIdx.x < 384) {
        int wave = threadIdx.x >> 6, lane = threadIdx.x & 63;
        int k = (blockIdx.x - 128) * 4 + wave;
        if (blockIdx.x == 128 && threadIdx.x == 0) ws[0] = 0.f;
        const float4 v = *reinterpret_cast<const float4*>(wgt + (size_t)k * DIM + lane * 4);
        float s = v.x * v.x + v.y * v.y + v.z * v.z + v.w * v.w;
        #pragma unroll
        for (int off = 32; off > 0; off >>= 1) s += __shfl_down(s, off, 64);
        if (lane == 0) ws[64 + k] = s + DIST_C;
    } else {
        u32* keys = reinterpret_cast<u32*>(ws + WS_KEYS);
        keys[(blockIdx.x - 384) * 256 + threadIdx.x] = 0xFFFFFFFFu;
    }
}

__device__ __forceinline__ void gl2lds16(const void* g, void* l) {
    __builtin_amdgcn_global_load_lds(
        (const __attribute__((address_space(1))) u32*)g,
        (__attribute__((address_space(3))) u32*)l, 16, 0, 0);
}

__launch_bounds__(256, 2)
__global__ void vq_kernel(const float* __restrict__ in,
                          float* __restrict__ ws) {
    // LDS: [0,32K) xs fp8 x-tile frag-ordered; [32K,64K) cb slice; [64K,+512) eno
    __shared__ __align__(16) unsigned char smem[66048];
    unsigned char* xs = smem;
    unsigned char* cbl = smem + 32768;
    float* eno = reinterpret_cast<float*>(smem + 65536);

    const int tid = threadIdx.x;
    const int lane = tid & 63;
    const int wv = tid >> 6;         // 4 waves
    const int wr = wv >> 1;          // row half:  rows [wr*64, +64)
    const int wc = wv & 1;           // code half: slice-codes [wc*64, +64)
    const int tx = lane & 15;
    const int tz = lane >> 4;

    // XCD-swizzle: all 8 slice-blocks of a tile land on one XCD, back-to-back
    const int bid = blockIdx.x;
    const int t  = (bid & 7) * 32 + (bid >> 6);   // row-tile 0..255 (128 rows)
    const int sc = (bid >> 3) & 7;                // code-slice 0..7 (128 codes)
    const int bb = t >> 3;
    const int hw0 = (t & 7) << 7;
    const float* inb = in + (size_t)bb * (DIM * HWDIM) + hw0;

    // ---- burst-stage cb slice (8 gl2lds/thread, all in flight) ----
    const unsigned char* cbg = reinterpret_cast<const unsigned char*>(ws + WS_CB)
                               + (size_t)sc * 32768;
    #pragma unroll
    for (int i = 0; i < 8; ++i)
        gl2lds16(cbg + i * 4096 + tid * 16, cbl + i * 4096 + tid * 16);

    // ---- eno slice ----
    if (tid < 128) eno[tid] = ws[64 + sc * 128 + tid];

    // ---- stage x: fp32 [d][hw] -> fp8 frag-ordered LDS; exact xsq on the fly ----
    float xsq = 0.f;
    {
        const int hw4 = (tid & 31) << 2;      // 4 local rows
        const int dq = tid >> 5;              // 0..7
        #pragma unroll
        for (int it = 0; it < 8; ++it) {
            int d0 = dq * 4 + it * 32;
            float4 r0 = *reinterpret_cast<const float4*>(inb + (size_t)(d0 + 0) * HWDIM + hw4);
            float4 r1 = *reinterpret_cast<const float4*>(inb + (size_t)(d0 + 1) * HWDIM + hw4);
            float4 r2 = *reinterpret_cast<const float4*>(inb + (size_t)(d0 + 2) * HWDIM + hw4);
            float4 r3 = *reinterpret_cast<const float4*>(inb + (size_t)(d0 + 3) * HWDIM + hw4);
            xsq += r0.x * r0.x + r0.y * r0.y + r0.z * r0.z + r0.w * r0.w
                 + r1.x * r1.x + r1.y * r1.y + r1.z * r1.z + r1.w * r1.w
                 + r2.x * r2.x + r2.y * r2.y + r2.z * r2.z + r2.w * r2.w
                 + r3.x * r3.x + r3.y * r3.y + r3.z * r3.z + r3.w * r3.w;
            float q0[4] = {r0.x, r0.y, r0.z, r0.w};
            float q1[4] = {r1.x, r1.y, r1.z, r1.w};
            float q2[4] = {r2.x, r2.y, r2.z, r2.w};
            float q3[4] = {r3.x, r3.y, r3.z, r3.w};
            #pragma unroll
            for (int jj = 0; jj < 4; ++jj) {
                int lr = hw4 + jj;            // local row 0..127
                u32 w = 0;
                w = __builtin_amdgcn_cvt_pk_fp8_f32(q0[jj], q1[jj], w, false);
                w = __builtin_amdgcn_cvt_pk_fp8_f32(q2[jj], q3[jj], w, true);
                // frag addr: rg=lr>>4, s=it, lane=(lr&15)|((dq>>1)<<4), e=(dq&1)*4
                *reinterpret_cast<u32*>(xs + (lr >> 4) * 4096 + it * 512
                                        + (((lr & 15) | ((dq >> 1) << 4)) << 3)
                                        + ((dq & 1) << 2)) = w;
            }
        }
    }

    asm volatile("s_waitcnt vmcnt(0)" ::: "memory");
    __syncthreads();   // the only barrier: xs + cbl + eno all ready, never rewritten

    // ---- hoist A fragments: rows (wr*4+rf)*16 + tx ----
    long af[4][8];
    #pragma unroll
    for (int rf = 0; rf < 4; ++rf) {
        #pragma unroll
        for (int s = 0; s < 8; ++s)
            af[rf][s] = *reinterpret_cast<const long*>(
                xs + (wr * 4 + rf) * 4096 + s * 512 + lane * 8);
    }

    float minkey[16];
    #pragma unroll
    for (int q = 0; q < 16; ++q) minkey[q] = 1e30f;

    // ---- compute: 4 code-groups x (8 ds_read_b64 + 32 MFMA + argmin), all LDS ----
    #pragma unroll
    for (int cg = 0; cg < 4; ++cg) {
        const int gi = wc * 4 + cg;
        const unsigned char* cbp = cbl + gi * 4096 + lane * 8;
        long bf[8];
        #pragma unroll
        for (int s = 0; s < 8; ++s)
            bf[s] = *reinterpret_cast<const long*>(cbp + s * 512);
        fx4 acc[4];
        const fx4 z = {0.f, 0.f, 0.f, 0.f};
        #pragma unroll
        for (int rf = 0; rf < 4; ++rf) acc[rf] = z;
        __builtin_amdgcn_s_setprio(1);
        #pragma unroll
        for (int s = 0; s < 8; ++s) {
            #pragma unroll
            for (int rf = 0; rf < 4; ++rf)
                acc[rf] = __builtin_amdgcn_mfma_f32_16x16x32_fp8_fp8(af[rf][s], bf[s], acc[rf], 0, 0, 0);
        }
        __builtin_amdgcn_s_setprio(0);
        const int codebase = sc * 128 + gi * 16 + tx;
        const float en = eno[gi * 16 + tx];
        #pragma unroll
        for (int rf = 0; rf < 4; ++rf) {
            #pragma unroll
            for (int r = 0; r < 4; ++r) {
                float d = fmaf(NEG2_OVER_ESCALE, acc[rf][r], en);
                u32 u = (__builtin_bit_cast(u32, d) & 0xFFFFFC00u) | (u32)codebase;
                minkey[rf * 4 + r] = fminf(minkey[rf * 4 + r], __builtin_bit_cast(float, u));
            }
        }
    }

    // ---- reduce over the 16 col-lanes (stays within tz-group) ----
    #pragma unroll
    for (int q = 0; q < 16; ++q) {
        float v = minkey[q];
        #pragma unroll
        for (int off = 1; off < 16; off <<= 1)
            v = fminf(v, __shfl_xor(v, off, 64));
        minkey[q] = v;
    }

    // ---- global argmin combine: atomicMin on bit-packed keys ----
    u32* keys = reinterpret_cast<u32*>(ws + WS_KEYS) + t * 128 + wr * 64;
    if (tx == 0) {
        #pragma unroll
        for (int rf = 0; rf < 4; ++rf) {
            #pragma unroll
            for (int r = 0; r < 4; ++r)
                atomicMin(&keys[rf * 16 + tz * 4 + r],
                          __builtin_bit_cast(u32, minkey[rf * 4 + r]));
        }
    }

    // ---- exact xsq: added once per tile (sc==0 blocks only) ----
    #pragma unroll
    for (int off = 32; off > 0; off >>= 1) xsq += __shfl_down(xsq, off, 64);
    if (sc == 0 && lane == 0) atomicAdd(&ws[0], xsq);
}

__global__ void scatter_kernel(const float* __restrict__ wgt,
                               float* __restrict__ ws,
                               float* __restrict__ out) {
    __shared__ int idxs[64];
    const int tid = threadIdx.x;
    const int bid = blockIdx.x;
    const int r0 = bid * 64;
    const u32* keys = reinterpret_cast<const u32*>(ws + WS_KEYS);
    if (tid < 64) {
        u32 k = keys[r0 + tid];
        idxs[tid] = (int)(k & 0x3FFu);
        float dsel = __builtin_bit_cast(float, k & 0xFFFFFC00u) - DIST_C;
        #pragma unroll
        for (int off = 32; off > 0; off >>= 1) dsel += __shfl_down(dsel, off, 64);
        if (tid == 0) atomicAdd(&ws[0], dsel);
    }
    __syncthreads();
    const int bb = r0 >> 10;
    const int hwb = r0 & 1023;
    const int hw4 = (tid & 15) << 2;
    const int dq = tid >> 4;
    int k0 = idxs[hw4 + 0], k1 = idxs[hw4 + 1];
    int k2 = idxs[hw4 + 2], k3 = idxs[hw4 + 3];
    const float* e0 = wgt + (size_t)k0 * DIM;
    const float* e1 = wgt + (size_t)k1 * DIM;
    const float* e2 = wgt + (size_t)k2 * DIM;
    const float* e3 = wgt + (size_t)k3 * DIM;
    float* outb = out + (size_t)bb * (DIM * HWDIM) + hwb;
    #pragma unroll
    for (int m = 0; m < 4; ++m) {
        int d0 = dq * 16 + m * 4;
        float4 r0v = *reinterpret_cast<const float4*>(e0 + d0);
        float4 r1v = *reinterpret_cast<const float4*>(e1 + d0);
        float4 r2v = *reinterpret_cast<const float4*>(e2 + d0);
        float4 r3v = *reinterpret_cast<const float4*>(e3 + d0);
        float er0[4] = {r0v.x, r0v.y, r0v.z, r0v.w};
        float er1[4] = {r1v.x, r1v.y, r1v.z, r1v.w};
        float er2[4] = {r2v.x, r2v.y, r2v.z, r2v.w};
        float er3[4] = {r3v.x, r3v.y, r3v.z, r3v.w};
        #pragma unroll
        for (int qd = 0; qd < 4; ++qd) {
            float4 ev = {er0[qd], er1[qd], er2[qd], er3[qd]};
            *reinterpret_cast<float4*>(outb + (size_t)(d0 + qd) * HWDIM + hw4) = ev;
        }
    }
}

__global__ void loss_kernel(const float* __restrict__ ws, float* __restrict__ out_loss) {
    out_loss[0] = (1.f + BETA) * ws[0] / (float)NTOT;
}

extern "C" void kernel_launch(void* const* d_in, const int* in_sizes, int n_in,
                              void* d_out, int out_size, void* d_ws, size_t ws_size,
                              hipStream_t stream) {
    const float* enc = (const float*)d_in[0];
    const float* wgt = (const float*)d_in[1];
    float* out = (float*)d_out;
    float* ws = (float*)d_ws;

    prep_kernel<<<512, 256, 0, stream>>>(wgt, ws);
    vq_kernel<<<2048, 256, 0, stream>>>(enc, ws);
    scatter_kernel<<<512, 256, 0, stream>>>(wgt, ws, out);
    loss_kernel<<<1, 1, 0, stream>>>(ws, out + NTOT);
}